// Round 1
// 610.640 us; speedup vs baseline: 1.1342x; 1.1342x over previous
//
#include <hip/hip_runtime.h>

// ImplicitResampleModule on MI355X (gfx950). Round: occupancy + structure.
// - 3 blocks/CU (LDS 52992 B, __launch_bounds__(256,3), 12 waves/CU)
// - sK eliminated: bk cancels in softmax; logits computed from accK regs
//   via same-wave sQ reads + shfl_xor butterfly (4 barriers instead of 6)
// - sV XOR-swizzled (16B blocks, key=(row>>2)&7) -> conflict-free PV reads
// - sA stride 36 -> conflict-free f32x4 attention-weight reads
// - v_cvt_pk_bf16_f32 for all paired f32->bf16 conversions
//
// d_ws layout (use_t: ws >= 68,552,192 B):
//   [0, 64MB)            featT  u16 [B][HW][C]
//   [64MB, +1MB)         offsC  f32 [B*THW*2]
//   [+1MB, +128K ...)    WqC, WkC, WvC  u16[65536] each
//   [+1MB+384K, ...)     bqC, bkC, bvC  u16[256] each (512 B apart)

using short8 = __attribute__((ext_vector_type(8))) short;   // 8 bf16
using uint4v = __attribute__((ext_vector_type(4))) unsigned;
using f32x4  = __attribute__((ext_vector_type(4))) float;
typedef unsigned short u16;

#define LOG2_1E4 13.287712379549449f
#define TWO_PI   6.283185307179586f
#define ATT_SCL  0.17677669529663687f   // 32^-0.5

__device__ __forceinline__ float bs2f(u16 s) {
    unsigned u = ((unsigned)s) << 16;
    float f; __builtin_memcpy(&f, &u, 4); return f;
}
__device__ __forceinline__ u16 f2bs(float f) {
    unsigned u; __builtin_memcpy(&u, &f, 4);
    u += 0x7fffu + ((u >> 16) & 1u);   // RNE
    return (u16)(u >> 16);
}
// HW packed f32->bf16 (RNE): dst.lo = bf16(lo), dst.hi = bf16(hi)
__device__ __forceinline__ unsigned cvt_pk_bf16(float lo, float hi) {
    unsigned r;
    asm("v_cvt_pk_bf16_f32 %0, %1, %2" : "=v"(r) : "v"(lo), "v"(hi));
    return r;
}

// Probe: bf16-decode offs at even u16 indices. Block-uniform result.
__device__ __forceinline__ int probe_is_f32(const u16* offs_raw) {
    const int lane = threadIdx.x & 63;
    const float v = bs2f(offs_raw[lane * 2]);
    const float av = fabsf(v);
    const bool insane = !(av >= 1e-3f && av <= 1000.0f);   // NaN -> insane
    return __popcll(__ballot(insane)) >= 16 ? 1 : 0;
}

// ---------------- canonicalize offs / weights / biases ----------------
__global__ __launch_bounds__(256) void irm_canon(
    const void* offs_raw, const void* Wq_r, const void* bq_r,
    const void* Wk_r, const void* bk_r, const void* Wv_r, const void* bv_r,
    unsigned char* canon)
{
    const int is_f32 = probe_is_f32((const u16*)offs_raw);
    float* offsC = (float*)canon;
    u16* WqC = (u16*)(canon + (1u << 20));
    u16* WkC = (u16*)(canon + (1u << 20) + (1u << 17));
    u16* WvC = (u16*)(canon + (1u << 20) + (2u << 17));
    u16* bqC = (u16*)(canon + (1u << 20) + (3u << 17));
    u16* bkC = bqC + 256;
    u16* bvC = bkC + 256;

    const int gid = blockIdx.x * 256 + threadIdx.x;
    if (gid < 262144) {
        offsC[gid] = is_f32 ? ((const float*)offs_raw)[gid]
                            : bs2f(((const u16*)offs_raw)[gid]);
    } else if (gid < 262144 + 3 * 65536) {
        const int r = gid - 262144, w = r >> 16, i = r & 65535;
        const void* src = (w == 0) ? Wq_r : (w == 1) ? Wk_r : Wv_r;
        u16*       dst  = (w == 0) ? WqC  : (w == 1) ? WkC  : WvC;
        dst[i] = is_f32 ? f2bs(((const float*)src)[i]) : ((const u16*)src)[i];
    } else if (gid < 262144 + 3 * 65536 + 3 * 256) {
        const int r = gid - 262144 - 3 * 65536, w = r >> 8, i = r & 255;
        const void* src = (w == 0) ? bq_r : (w == 1) ? bk_r : bv_r;
        u16*       dst  = (w == 0) ? bqC  : (w == 1) ? bkC  : bvC;
        dst[i] = is_f32 ? f2bs(((const float*)src)[i]) : ((const u16*)src)[i];
    }
}

// ---------------- transpose feat [B,C,HW] -> featT bf16 [B,HW,C] ----------------
// tile[64][72], XOR-swizzled 8-u16 blocks keyed on (row>>3)&7 -> conflict-free
// transposed reads; packed cvt; short8 (16B) global stores.
__global__ __launch_bounds__(256) void irm_transpose(const void* __restrict__ feat_raw,
                                                     const u16* __restrict__ offs_raw,
                                                     u16* __restrict__ featT) {
    const int is_f32 = probe_is_f32(offs_raw);
    __shared__ u16 tile[64][72];
    const int b   = blockIdx.z;
    const int c0  = blockIdx.y << 6;
    const int hw0 = blockIdx.x << 6;
    const int tid = threadIdx.x;
    const int r    = tid >> 4;          // 0..15
    const int col4 = (tid & 15) << 2;   // 0..60
    #pragma unroll
    for (int it = 0; it < 4; ++it) {
        const int c = (it << 4) + r;
        const size_t idx = ((size_t)((b << 8) + c0 + c) << 16) + hw0 + col4;
        ushort4 o;
        if (is_f32) {
            const float4 v = *(const float4*)((const float*)feat_raw + idx);
            const unsigned lo = cvt_pk_bf16(v.x, v.y);
            const unsigned hi = cvt_pk_bf16(v.z, v.w);
            o.x = (u16)(lo & 0xffffu); o.y = (u16)(lo >> 16);
            o.z = (u16)(hi & 0xffffu); o.w = (u16)(hi >> 16);
        } else {
            o = *(const ushort4*)((const u16*)feat_raw + idx);
        }
        *(ushort4*)&tile[c][col4 ^ (((c >> 3) & 7) << 3)] = o;
    }
    __syncthreads();
    const int s = tid & 7;    // c-octet
    const int m = tid >> 3;   // hw within half-tile
    #pragma unroll
    for (int it2 = 0; it2 < 2; ++it2) {
        const int hw = (it2 << 5) + m;
        short8 o;
        #pragma unroll
        for (int k = 0; k < 8; ++k) {
            const int c = (s << 3) + k;
            o[k] = (short)tile[c][hw ^ (((c >> 3) & 7) << 3)];
        }
        u16* dst = featT + (((size_t)((b << 16) + hw0 + hw)) << 8) + c0 + (s << 3);
        *(short8*)dst = o;
    }
}

// ---------------- main fused kernel ----------------
__global__ __launch_bounds__(256, 3) void irm_main(
    const void* __restrict__ fsrc,   // featT (bf16) if transposed else raw feat
    const int transposed,
    const u16* __restrict__ offs_raw,
    const float* __restrict__ offsC,
    const u16* __restrict__ Wq, const u16* __restrict__ bq,
    const u16* __restrict__ Wk, const u16* __restrict__ bk_unused,
    const u16* __restrict__ Wv, const u16* __restrict__ bv,
    void* __restrict__ out_raw)
{
    const int is_f32 = probe_is_f32(offs_raw);

    // LDS 52992 B -> 3 blocks/CU.
    //  [0,1024)      pe1 f32[256]      (dead after phase 0b)
    //  [1024,2048)   invtab f32[256]   (dead after phase 0b)
    //  [0,2304)      sA f32[16][36]    (overlay, written post-B2)
    //  [2304,36096)  sFw u16[64][264]  (dead after V GEMM) / sV overlay
    //  [36096,44544) sFb u16[16][264]
    //  [44544,52992) sQ  u16[16][264]
    __shared__ __align__(16) unsigned char smem[52992];
    float* pe1    = (float*)smem;
    float* invtab = (float*)(smem + 1024);
    float* sA     = (float*)smem;             // [16][36] f32 (stride 36 -> bank-uniform f32x4)
    u16*   sFw    = (u16*)(smem + 2304);      // [64][264]
    u16*   sV     = (u16*)(smem + 2304);      // overlays sFw (phase 2)
    u16*   sFb    = (u16*)(smem + 36096);     // [16][264]
    u16*   sQ     = (u16*)(smem + 44544);     // [16][264]

    const int tid = threadIdx.x;
    const int raw = blockIdx.x;
    const int wq_ = ((raw & 7) << 10) | (raw >> 3);   // XCD swizzle (bijective: 8192 % 8 == 0)
    const int b   = wq_ >> 12;
    const int t0  = (wq_ & 4095) << 4;

    // hoist offset load (latency overlaps phase 0a)
    const int p0 = tid >> 4;            // pixel 0..15
    const int cx = tid & 15;            // 16-channel group
    const int t  = t0 + p0;
    const float offx = offsC[((((size_t)b << 16) + (size_t)t) << 1) + 0];
    const float offy = offsC[((((size_t)b << 16) + (size_t)t) << 1) + 1];

    // ---- phase 0a: PE tables. posb is redundant (base in {0,1}):
    // pe1[c] = PE value at base=1; base=0 value is (c&1)?1:0 (computed inline).
    {
        const int c = tid;
        const int j = (c & 127) >> 1;
        const float invt = exp2f(-(float)j * (LOG2_1E4 / 64.0f));
        const float arg = (TWO_PI / (1.0f + 1e-6f)) * invt;
        pe1[c]    = (c & 1) ? __cosf(arg) : __sinf(arg);
        invtab[c] = invt;
    }
    __syncthreads();   // B1

    // ---- phase 0b: gather + stage fw, fb ----
    {
        const int ty = t >> 8, tx = t & 255;
        const float fy = (float)ty + offy;
        const float fx = (float)tx + offx;
        const float fiy = floorf(fy), fix = floorf(fx);
        const int iy = (int)fiy, ix = (int)fix;
        const float dy = fy - fiy, dx = fx - fix;

        int lin4[4];
        #pragma unroll
        for (int u = 0; u < 4; ++u) {
            int hy = iy + (u >> 1); hy = hy < 0 ? 0 : (hy > 255 ? 255 : hy);
            int wx = ix + (u & 1);  wx = wx < 0 ? 0 : (wx > 255 ? 255 : wx);
            lin4[u] = (hy << 8) | wx;
        }

        short8 g[4][2];
        if (transposed) {
            #pragma unroll
            for (int u = 0; u < 4; ++u) {       // all 8 loads issued up front
                const u16* src = (const u16*)fsrc +
                    ((((size_t)(b << 16)) + (size_t)lin4[u]) << 8) + (cx << 4);
                g[u][0] = *(const short8*)(src);
                g[u][1] = *(const short8*)(src + 8);
            }
        } else {
            #pragma unroll
            for (int u = 0; u < 4; ++u) {
                #pragma unroll
                for (int i = 0; i < 8; ++i) {
                    const size_t i0 = (((size_t)((b << 8) + (cx << 4) + i)) << 16) + lin4[u];
                    const size_t i1 = (((size_t)((b << 8) + (cx << 4) + 8 + i)) << 16) + lin4[u];
                    g[u][0][i] = is_f32 ? (short)f2bs(((const float*)fsrc)[i0]) : (short)((const u16*)fsrc)[i0];
                    g[u][1][i] = is_f32 ? (short)f2bs(((const float*)fsrc)[i1]) : (short)((const u16*)fsrc)[i1];
                }
            }
        }

        float pe1v[16], invtv[16];
        #pragma unroll
        for (int i = 0; i < 16; ++i) {
            pe1v[i]  = pe1[(cx << 4) + i];
            invtv[i] = invtab[(cx << 4) + i];
        }

        const bool hi_half = (cx >= 8);   // c >= 128 -> x-PE half
        float gsum[16];
        #pragma unroll
        for (int i = 0; i < 16; ++i) gsum[i] = 0.0f;

        #pragma unroll
        for (int u = 0; u < 4; ++u) {
            const bool sel = hi_half ? (bool)(u & 1) : (bool)(u >> 1);
            unsigned pk[8];
            #pragma unroll
            for (int i2 = 0; i2 < 8; ++i2) {
                float w2[2];
                #pragma unroll
                for (int k = 0; k < 2; ++k) {
                    const int i = i2 * 2 + k;
                    const float f = bs2f((u16)g[u][i >> 3][i & 7]);
                    gsum[i] += f;
                    const float pz = (i & 1) ? 1.0f : 0.0f;
                    w2[k] = f + (sel ? pe1v[i] : pz);
                }
                pk[i2] = cvt_pk_bf16(w2[0], w2[1]);
            }
            const uint4v lo = {pk[0], pk[1], pk[2], pk[3]};
            const uint4v hi = {pk[4], pk[5], pk[6], pk[7]};
            *(uint4v*)&sFw[((p0 << 2) + u) * 264 + (cx << 4)]     = lo;
            *(uint4v*)&sFw[((p0 << 2) + u) * 264 + (cx << 4) + 8] = hi;
        }

        // fb = mean_u + PE(deci, card = 2)
        const float ys = dy * (TWO_PI / (2.0f + 1e-6f));
        const float xs = dx * (TWO_PI / (2.0f + 1e-6f));
        const float sxy = hi_half ? xs : ys;
        unsigned qk[8];
        #pragma unroll
        for (int i2 = 0; i2 < 8; ++i2) {
            float v2[2];
            #pragma unroll
            for (int k = 0; k < 2; ++k) {
                const int i = i2 * 2 + k;
                const float arg = sxy * invtv[i];
                const float pe = (i & 1) ? __cosf(arg) : __sinf(arg);
                v2[k] = gsum[i] * 0.25f + pe;
            }
            qk[i2] = cvt_pk_bf16(v2[0], v2[1]);
        }
        const uint4v qlo = {qk[0], qk[1], qk[2], qk[3]};
        const uint4v qhi = {qk[4], qk[5], qk[6], qk[7]};
        *(uint4v*)&sFb[p0 * 264 + (cx << 4)]     = qlo;
        *(uint4v*)&sFb[p0 * 264 + (cx << 4) + 8] = qhi;
    }
    __syncthreads();   // B2

    // ---- phase 1: projections. Wave w owns cols [64w, 64w+64) = heads {2w,2w+1}.
    const int lane = tid & 63;
    const int wv   = tid >> 6;
    const int c15  = lane & 15;
    const int qd   = lane >> 4;
    const int colbase = wv << 6;
    const f32x4 zero4 = {0.f, 0.f, 0.f, 0.f};

    // Q = fb @ Wq^T (+bq) -> sQ bf16 (read back only by the same wave)
    {
        f32x4 accQ[4];
        #pragma unroll
        for (int nt = 0; nt < 4; ++nt) accQ[nt] = zero4;
        #pragma unroll
        for (int ks = 0; ks < 8; ++ks) {
            short8 aq = *(const short8*)&sFb[c15 * 264 + ks * 32 + qd * 8];
            #pragma unroll
            for (int nt = 0; nt < 4; ++nt) {
                short8 bw = *(const short8*)&Wq[(colbase + nt * 16 + c15) * 256 + ks * 32 + qd * 8];
                accQ[nt] = __builtin_amdgcn_mfma_f32_16x16x32_bf16(aq, bw, accQ[nt], 0, 0, 0);
            }
        }
        #pragma unroll
        for (int nt = 0; nt < 4; ++nt) {
            const int n = colbase + nt * 16 + c15;
            const float bias = bs2f(bq[n]);
            #pragma unroll
            for (int rp = 0; rp < 2; ++rp) {
                const unsigned pk = cvt_pk_bf16(accQ[nt][2 * rp] + bias, accQ[nt][2 * rp + 1] + bias);
                sQ[(qd * 4 + 2 * rp)     * 264 + n] = (u16)(pk & 0xffffu);
                sQ[(qd * 4 + 2 * rp + 1) * 264 + n] = (u16)(pk >> 16);
            }
        }
    }
    asm volatile("" ::: "memory");   // compiler fence: same-wave sQ write -> read (DS is in-order per wave)

    // K = fw @ Wk^T. NO bk: per-(p,h) it is u-independent -> cancels in softmax.
    f32x4 accK[4][4];
    #pragma unroll
    for (int m = 0; m < 4; ++m)
        #pragma unroll
        for (int nt = 0; nt < 4; ++nt) accK[m][nt] = zero4;
    #pragma unroll
    for (int ks = 0; ks < 8; ++ks) {
        short8 af[4], bfr[4];
        #pragma unroll
        for (int m = 0; m < 4; ++m)
            af[m] = *(const short8*)&sFw[(m * 16 + c15) * 264 + ks * 32 + qd * 8];
        #pragma unroll
        for (int nt = 0; nt < 4; ++nt)
            bfr[nt] = *(const short8*)&Wk[(colbase + nt * 16 + c15) * 256 + ks * 32 + qd * 8];
        #pragma unroll
        for (int m = 0; m < 4; ++m)
            #pragma unroll
            for (int nt = 0; nt < 4; ++nt)
                accK[m][nt] = __builtin_amdgcn_mfma_f32_16x16x32_bf16(af[m], bfr[nt], accK[m][nt], 0, 0, 0);
    }

    // ---- logits + softmax from accK registers (no sK, no extra barrier) ----
    // acc element (m,nt,r): K[kvrow=16m+4qd+r][n=colbase+16nt+c15]
    //   -> pixel p = 4m+qd, window u = r, head h = 2wv + (nt>>1).
    // part[m][r][h2] = sum over this lane's channels; butterfly over c15 completes the dot.
    {
        float part[4][4][2];
        #pragma unroll
        for (int m = 0; m < 4; ++m)
            #pragma unroll
            for (int r = 0; r < 4; ++r) { part[m][r][0] = 0.f; part[m][r][1] = 0.f; }
        #pragma unroll
        for (int m = 0; m < 4; ++m) {
            #pragma unroll
            for (int nt = 0; nt < 4; ++nt) {
                const float qv = bs2f(sQ[(4 * m + qd) * 264 + colbase + nt * 16 + c15]);
                #pragma unroll
                for (int r = 0; r < 4; ++r)
                    part[m][r][nt >> 1] += accK[m][nt][r] * qv;
            }
        }
        #pragma unroll
        for (int m = 0; m < 4; ++m)
            #pragma unroll
            for (int r = 0; r < 4; ++r)
                #pragma unroll
                for (int h2 = 0; h2 < 2; ++h2) {
                    float v = part[m][r][h2];
                    v += __shfl_xor(v, 1);
                    v += __shfl_xor(v, 2);
                    v += __shfl_xor(v, 4);
                    v += __shfl_xor(v, 8);
                    part[m][r][h2] = v;
                }
        // softmax over u=r; results replicated across c15 group -> lanes 0/8 write sA
        auto smax_write = [&](const float (&pm)[4][2], const int p) {
            #pragma unroll
            for (int h2 = 0; h2 < 2; ++h2) {
                const float l0 = pm[0][h2] * ATT_SCL, l1 = pm[1][h2] * ATT_SCL;
                const float l2 = pm[2][h2] * ATT_SCL, l3 = pm[3][h2] * ATT_SCL;
                const float mx = fmaxf(fmaxf(l0, l1), fmaxf(l2, l3));
                const float e0 = __expf(l0 - mx), e1 = __expf(l1 - mx);
                const float e2 = __expf(l2 - mx), e3 = __expf(l3 - mx);
                const float inv = __fdividef(1.0f, e0 + e1 + e2 + e3);
                float* ap = &sA[p * 36 + ((wv << 1) + h2) * 4];
                ap[0] = e0 * inv; ap[1] = e1 * inv; ap[2] = e2 * inv; ap[3] = e3 * inv;
            }
        };
        if      (c15 == 0) { smax_write(part[0], qd);     smax_write(part[1], 4 + qd);  }
        else if (c15 == 8) { smax_write(part[2], 8 + qd); smax_write(part[3], 12 + qd); }
    }
    // accK dead here -> accV reuses the same registers (keeps us under the 3-wave cap)

    // V = fw @ Wv^T
    f32x4 accV[4][4];
    #pragma unroll
    for (int m = 0; m < 4; ++m)
        #pragma unroll
        for (int nt = 0; nt < 4; ++nt) accV[m][nt] = zero4;
    #pragma unroll
    for (int ks = 0; ks < 8; ++ks) {
        short8 af[4], bfr[4];
        #pragma unroll
        for (int m = 0; m < 4; ++m)
            af[m] = *(const short8*)&sFw[(m * 16 + c15) * 264 + ks * 32 + qd * 8];
        #pragma unroll
        for (int nt = 0; nt < 4; ++nt)
            bfr[nt] = *(const short8*)&Wv[(colbase + nt * 16 + c15) * 256 + ks * 32 + qd * 8];
        #pragma unroll
        for (int m = 0; m < 4; ++m)
            #pragma unroll
            for (int nt = 0; nt < 4; ++nt)
                accV[m][nt] = __builtin_amdgcn_mfma_f32_16x16x32_bf16(af[m], bfr[nt], accV[m][nt], 0, 0, 0);
    }
    __syncthreads();   // B3: all waves done with sFw; sA visible

    // ---- write sV (+bv), XOR-swizzled 8-u16 blocks: idx = row*264 + (n ^ (((row>>2)&7)<<3))
    #pragma unroll
    for (int nt = 0; nt < 4; ++nt) {
        const int n = colbase + nt * 16 + c15;
        const float bias = bs2f(bv[n]);
        #pragma unroll
        for (int m = 0; m < 4; ++m) {
            #pragma unroll
            for (int rp = 0; rp < 2; ++rp) {
                const int row = m * 16 + qd * 4 + 2 * rp;
                const int ns = n ^ (((row >> 2) & 7) << 3);   // same key for row and row+1
                const unsigned pk = cvt_pk_bf16(accV[m][nt][2 * rp] + bias, accV[m][nt][2 * rp + 1] + bias);
                sV[row * 264 + ns]       = (u16)(pk & 0xffffu);
                sV[(row + 1) * 264 + ns] = (u16)(pk >> 16);
            }
        }
    }
    __syncthreads();   // B4: sV visible

    // ---- PV + store: thread (p, h, dh) handles 16 output channels ----
    {
        const int p  = tid & 15;
        const int h  = (tid >> 4) & 7;
        const int dh = tid >> 7;
        const f32x4 a4 = *(const f32x4*)&sA[p * 36 + h * 4];
        float acc[16];
        #pragma unroll
        for (int i = 0; i < 16; ++i) acc[i] = 0.0f;
        #pragma unroll
        for (int u = 0; u < 4; ++u) {
            const int row = p * 4 + u;
            const int f = ((row >> 2) & 7) << 3;    // = (p&7)<<3
            const int cb = h * 32 + dh * 16;
            const short8 v0 = *(const short8*)&sV[row * 264 + (cb ^ f)];
            const short8 v1 = *(const short8*)&sV[row * 264 + ((cb + 8) ^ f)];
            const float a = a4[u];
            #pragma unroll
            for (int i = 0; i < 8; ++i) {
                acc[i]     += a * bs2f((u16)v0[i]);
                acc[i + 8] += a * bs2f((u16)v1[i]);
            }
        }
        const size_t base = (((size_t)((b << 8) + h * 32 + dh * 16)) << 16) + t0 + p;
        if (is_f32) {
            float* dst = (float*)out_raw + base;
            #pragma unroll
            for (int i = 0; i < 16; ++i)
                __builtin_nontemporal_store(acc[i], dst + ((size_t)i << 16));
        } else {
            u16* dst = (u16*)out_raw + base;
            #pragma unroll
            for (int i = 0; i < 16; ++i)
                __builtin_nontemporal_store(f2bs(acc[i]), dst + ((size_t)i << 16));
        }
    }
}

extern "C" void kernel_launch(void* const* d_in, const int* in_sizes, int n_in,
                              void* d_out, int out_size, void* d_ws, size_t ws_size,
                              hipStream_t stream) {
    const size_t FEATT_BYTES = (size_t)1 << 26;   // 64 MB bf16 featT
    const size_t CANON_BYTES = (1u << 20) + (3u << 17) + 3 * 512;
    const int use_t = (ws_size >= FEATT_BYTES + CANON_BYTES) ? 1 : 0;   // ws_size constant -> capture-safe

    unsigned char* ws    = (unsigned char*)d_ws;
    unsigned char* canon = ws + (use_t ? FEATT_BYTES : 0);
    float* offsC = (float*)canon;
    u16* WqC = (u16*)(canon + (1u << 20));
    u16* WkC = (u16*)(canon + (1u << 20) + (1u << 17));
    u16* WvC = (u16*)(canon + (1u << 20) + (2u << 17));
    u16* bqC = (u16*)(canon + (1u << 20) + (3u << 17));
    u16* bkC = bqC + 256;
    u16* bvC = bkC + 256;

    irm_canon<<<1795, 256, 0, stream>>>(d_in[1], d_in[2], d_in[3], d_in[4],
                                        d_in[5], d_in[6], d_in[7], canon);
    if (use_t)
        irm_transpose<<<dim3(1024, 4, 2), 256, 0, stream>>>(d_in[0], (const u16*)d_in[1], (u16*)ws);
    irm_main<<<dim3(8192), 256, 0, stream>>>(use_t ? (const void*)ws : d_in[0], use_t,
                                             (const u16*)d_in[1], offsC,
                                             WqC, bqC, WkC, bkC, WvC, bvC, d_out);
}